// Round 1
// baseline (322.034 us; speedup 1.0000x reference)
//
#include <hip/hip_runtime.h>
#include <hip/hip_bf16.h>

// Fused Linear([16,8192,256]x[256,256]) + per-batch BatchNorm over N.
// bf16x3 split-GEMM (hi*hi + hi*lo + lo*hi) for fp32-class accuracy on MFMA.
// Bias b is dropped: BN subtracts the per-(b,o) mean, so a per-o constant
// cancels exactly (var unaffected).

typedef __attribute__((ext_vector_type(8))) __bf16 bf16x8;
typedef __attribute__((ext_vector_type(4))) float f32x4;
typedef __attribute__((ext_vector_type(8))) unsigned short ushort8;

#define BDIM   16
#define NDIM   8192
#define FIN    256
#define FOUT   256
#define BM     128
#define BN     128
#define BKSTEP 64
#define NTHREADS 256

// Split one fp32 into bf16 hi (truncate) + bf16 lo (truncate of residual).
// hi+lo captures ~16 mantissa bits -> bf16x3 product error ~2^-16 relative.
__device__ __forceinline__ void split_pack(const float4 v0, const float4 v1,
                                           ushort8& h, ushort8& l) {
  float f[8] = {v0.x, v0.y, v0.z, v0.w, v1.x, v1.y, v1.z, v1.w};
#pragma unroll
  for (int i = 0; i < 8; ++i) {
    unsigned int u  = __float_as_uint(f[i]);
    unsigned int hu = u & 0xFFFF0000u;
    h[i] = (unsigned short)(u >> 16);
    float rem = f[i] - __uint_as_float(hu);
    l[i] = (unsigned short)(__float_as_uint(rem) >> 16);
  }
}

// MODE 0: write y to Y(ws) + partial stats.  MODE 1: partial stats only.
// MODE 2: read per-(b,o) scale/shift Sc/Tc, write normalized output to Y(out).
template <int MODE>
__global__ __launch_bounds__(NTHREADS, 2)
void fused_gemm(const float* __restrict__ X, const float* __restrict__ W,
                float* __restrict__ Y,
                float* __restrict__ P1, float* __restrict__ P2,
                const float* __restrict__ Sc, const float* __restrict__ Tc) {
  __shared__ __align__(16) char lds[65536];
  char* Abh = lds;              // A hi: 128 rows x 64 k x bf16, XOR-swizzled
  char* Abl = lds + 16384;      // A lo
  char* Bbh = lds + 32768;      // B hi (W rows = output cols)
  char* Bbl = lds + 49152;      // B lo

  const int tid  = threadIdx.x;
  const int rblk = blockIdx.x;             // 0..1023  (row block of 128)
  const int cblk = blockIdx.y;             // 0..1     (col block of 128)
  const size_t rowBase = (size_t)rblk * BM;
  const int colBase = cblk * BN;

  const int wid  = tid >> 6;
  const int lane = tid & 63;
  const int wr   = wid >> 1;               // wave row (0..1) -> 64 rows
  const int wc   = wid & 1;                // wave col (0..1) -> 64 cols
  const int lg   = lane >> 4;              // lane group 0..3
  const int lr   = lane & 15;

  f32x4 acc[4][4];
#pragma unroll
  for (int m = 0; m < 4; ++m)
#pragma unroll
    for (int n = 0; n < 4; ++n) acc[m][n] = f32x4{0.f, 0.f, 0.f, 0.f};

  for (int ks = 0; ks < FIN / BKSTEP; ++ks) {
    const int k0 = ks * BKSTEP;
    // ---- stage: 128x64 fp32 of X and of W -> bf16 hi/lo in LDS ----
#pragma unroll
    for (int c = 0; c < 4; ++c) {
      int id = tid + c * NTHREADS;         // 0..1023
      int r  = id >> 3;                    // row 0..127
      int kc = id & 7;                     // 8-float chunk 0..7
      int boff = r * 128 + ((kc * 16) ^ ((r & 7) << 4));
      {
        const float4* ga = (const float4*)(X + (rowBase + r) * (size_t)FIN + k0 + kc * 8);
        ushort8 h, l;
        split_pack(ga[0], ga[1], h, l);
        *(ushort8*)(Abh + boff) = h;
        *(ushort8*)(Abl + boff) = l;
      }
      {
        const float4* gb = (const float4*)(W + (size_t)(colBase + r) * FIN + k0 + kc * 8);
        ushort8 h, l;
        split_pack(gb[0], gb[1], h, l);
        *(ushort8*)(Bbh + boff) = h;
        *(ushort8*)(Bbl + boff) = l;
      }
    }
    __syncthreads();
    // ---- compute: 2 k-slabs of 32, 4x4 fragments, 3 products (hh, hl, lh) ----
#pragma unroll
    for (int kk = 0; kk < 2; ++kk) {
      bf16x8 ah[4], al[4], bh[4], bl[4];
#pragma unroll
      for (int m = 0; m < 4; ++m) {
        int row  = wr * 64 + m * 16 + lr;
        int boff = row * 128 + ((kk * 64 + lg * 16) ^ ((row & 7) << 4));
        ah[m] = *(const bf16x8*)(Abh + boff);
        al[m] = *(const bf16x8*)(Abl + boff);
      }
#pragma unroll
      for (int n = 0; n < 4; ++n) {
        int row  = wc * 64 + n * 16 + lr;
        int boff = row * 128 + ((kk * 64 + lg * 16) ^ ((row & 7) << 4));
        bh[n] = *(const bf16x8*)(Bbh + boff);
        bl[n] = *(const bf16x8*)(Bbl + boff);
      }
#pragma unroll
      for (int m = 0; m < 4; ++m)
#pragma unroll
        for (int n = 0; n < 4; ++n) {
          acc[m][n] = __builtin_amdgcn_mfma_f32_16x16x32_bf16(ah[m], bh[n], acc[m][n], 0, 0, 0);
          acc[m][n] = __builtin_amdgcn_mfma_f32_16x16x32_bf16(ah[m], bl[n], acc[m][n], 0, 0, 0);
          acc[m][n] = __builtin_amdgcn_mfma_f32_16x16x32_bf16(al[m], bh[n], acc[m][n], 0, 0, 0);
        }
    }
    __syncthreads();
  }

  if (MODE == 0) {
    // write y tile (fp32) to workspace
#pragma unroll
    for (int m = 0; m < 4; ++m) {
      size_t row = rowBase + wr * 64 + m * 16 + lg * 4;
#pragma unroll
      for (int n = 0; n < 4; ++n) {
        int col = colBase + wc * 64 + n * 16 + lr;
#pragma unroll
        for (int r = 0; r < 4; ++r)
          Y[(row + r) * (size_t)FOUT + col] = acc[m][n][r];
      }
    }
  }

  if (MODE <= 1) {
    // per-column partial sums of y and y^2 over this block's 128 rows
    float ps1[4], ps2[4];
#pragma unroll
    for (int n = 0; n < 4; ++n) {
      ps1[n] = 0.f; ps2[n] = 0.f;
#pragma unroll
      for (int m = 0; m < 4; ++m)
#pragma unroll
        for (int r = 0; r < 4; ++r) {
          float v = acc[m][n][r];
          ps1[n] += v; ps2[n] += v * v;
        }
      ps1[n] += __shfl_xor(ps1[n], 16);
      ps1[n] += __shfl_xor(ps1[n], 32);
      ps2[n] += __shfl_xor(ps2[n], 16);
      ps2[n] += __shfl_xor(ps2[n], 32);
    }
    __syncthreads();                 // done reading A/B tiles; reuse LDS
    float* red = (float*)lds;        // [2][4 waves][64 cols]
    if (lr == lane) {}               // (no-op; clarity)
    if (lane < 16) {
#pragma unroll
      for (int n = 0; n < 4; ++n) {
        red[wid * 64 + n * 16 + lr]       = ps1[n];
        red[256 + wid * 64 + n * 16 + lr] = ps2[n];
      }
    }
    __syncthreads();
    if (tid < 128) {
      int ccb = tid >> 6, cc = tid & 63;   // waves wid=ccb and wid=2+ccb share cols
      float s1 = red[ccb * 64 + cc] + red[(2 + ccb) * 64 + cc];
      float s2 = red[256 + ccb * 64 + cc] + red[256 + (2 + ccb) * 64 + cc];
      P1[(size_t)rblk * FOUT + colBase + tid] = s1;
      P2[(size_t)rblk * FOUT + colBase + tid] = s2;
    }
  }

  if (MODE == 2) {
    const int b = rblk >> 6;         // 64 row-blocks per batch
#pragma unroll
    for (int n = 0; n < 4; ++n) {
      int col  = colBase + wc * 64 + n * 16 + lr;
      float sc = Sc[b * FOUT + col];
      float tc = Tc[b * FOUT + col];
#pragma unroll
      for (int m = 0; m < 4; ++m) {
        size_t row = rowBase + wr * 64 + m * 16 + lg * 4;
#pragma unroll
        for (int r = 0; r < 4; ++r)
          Y[(row + r) * (size_t)FOUT + col] = fmaf(acc[m][n][r], sc, tc);
      }
    }
  }
}

// Reduce 64 row-block partials per (b,o) -> scale/shift coefficients.
__global__ void reduce_stats(const float* __restrict__ P1, const float* __restrict__ P2,
                             const float* __restrict__ gamma, const float* __restrict__ beta,
                             float* __restrict__ Sc, float* __restrict__ Tc) {
  int t = blockIdx.x * blockDim.x + threadIdx.x;  // 0..4095 = (b,o)
  int b = t >> 8, o = t & 255;
  float s1 = 0.f, s2 = 0.f;
  for (int r = 0; r < 64; ++r) {
    size_t idx = ((size_t)(b * 64 + r)) * FOUT + o;
    s1 += P1[idx];
    s2 += P2[idx];
  }
  float mean = s1 * (1.f / (float)NDIM);
  float var  = s2 * (1.f / (float)NDIM) - mean * mean;
  float rstd = rsqrtf(var + 1e-5f);
  float g    = gamma[o] * rstd;
  Sc[t] = g;
  Tc[t] = beta[o] - mean * g;
}

// Elementwise normalize of materialized y (Plan A).
__global__ void normalize_y(const float4* __restrict__ Yv,
                            const float* __restrict__ Sc, const float* __restrict__ Tc,
                            float4* __restrict__ Ov) {
  const int total = (BDIM * NDIM * FOUT) / 4;  // 8388608
  for (int i = blockIdx.x * blockDim.x + threadIdx.x; i < total;
       i += gridDim.x * blockDim.x) {
    float4 y = Yv[i];
    size_t e = (size_t)i * 4;
    int o = (int)(e & 255);
    int b = (int)(e >> 21);                    // 8192*256 = 2^21 per batch
    const float4 s = *(const float4*)(Sc + b * 256 + o);
    const float4 t = *(const float4*)(Tc + b * 256 + o);
    float4 r;
    r.x = fmaf(y.x, s.x, t.x);
    r.y = fmaf(y.y, s.y, t.y);
    r.z = fmaf(y.z, s.z, t.z);
    r.w = fmaf(y.w, s.w, t.w);
    Ov[i] = r;
  }
}

extern "C" void kernel_launch(void* const* d_in, const int* in_sizes, int n_in,
                              void* d_out, int out_size, void* d_ws, size_t ws_size,
                              hipStream_t stream) {
  const float* X     = (const float*)d_in[0];
  const float* W     = (const float*)d_in[1];
  // d_in[2] = bias: mathematically cancelled by BatchNorm's mean subtraction.
  const float* gamma = (const float*)d_in[3];
  const float* beta  = (const float*)d_in[4];
  float* out = (float*)d_out;
  float* wsf = (float*)d_ws;

  const size_t yElems = (size_t)BDIM * NDIM * FOUT;      // 33,554,432
  const size_t pElems = 1024u * FOUT;                    // 262,144 per array
  const size_t needA  = (yElems + 2 * pElems + 2 * 4096) * sizeof(float);

  dim3 grid(1024, 2), blk(NTHREADS);
  if (ws_size >= needA) {
    // Plan A: materialize y in ws, single GEMM pass.
    float* Y  = wsf;
    float* P1 = wsf + yElems;
    float* P2 = P1 + pElems;
    float* Sc = P2 + pElems;
    float* Tc = Sc + 4096;
    fused_gemm<0><<<grid, blk, 0, stream>>>(X, W, Y, P1, P2, nullptr, nullptr);
    reduce_stats<<<16, 256, 0, stream>>>(P1, P2, gamma, beta, Sc, Tc);
    normalize_y<<<2048, 256, 0, stream>>>((const float4*)Y, Sc, Tc, (float4*)out);
  } else {
    // Plan A': stats pass + recompute pass (tiny ws footprint).
    float* P1 = wsf;
    float* P2 = P1 + pElems;
    float* Sc = P2 + pElems;
    float* Tc = Sc + 4096;
    fused_gemm<1><<<grid, blk, 0, stream>>>(X, W, nullptr, P1, P2, nullptr, nullptr);
    reduce_stats<<<16, 256, 0, stream>>>(P1, P2, gamma, beta, Sc, Tc);
    fused_gemm<2><<<grid, blk, 0, stream>>>(X, W, out, P1, P2, Sc, Tc);
  }
}